// Round 7
// baseline (4256.355 us; speedup 1.0000x reference)
//
#include <hip/hip_runtime.h>

// Problem constants
#define BB 2048   // batch
#define TT 128    // timesteps
#define VV 25     // input features
#define HH 512    // hidden
#define NC 100    // classes

typedef __attribute__((ext_vector_type(8))) short short8;
typedef __attribute__((ext_vector_type(4))) float f32x4;

__device__ __forceinline__ float fsigmoid(float x) { return 1.0f / (1.0f + __expf(-x)); }
__device__ __forceinline__ float ftanh(float x) {
    float e = __expf(2.0f * x);
    return 1.0f - 2.0f / (e + 1.0f);
}

// fp32 -> bf16 hi + bf16 lo (RNE both); hi+lo carries ~16 mantissa bits.
__device__ __forceinline__ void split2(float f, short& hi, short& lo) {
    unsigned u = __float_as_uint(f);
    unsigned hb = (u + 0x7FFFu + ((u >> 16) & 1u)) >> 16;
    float hf = __uint_as_float(hb << 16);
    float r = f - hf;                      // exact
    unsigned v = __float_as_uint(r);
    unsigned lb = (v + 0x7FFFu + ((v >> 16) & 1u)) >> 16;
    hi = (short)hb;
    lo = (short)lb;
}

// ---- prep: weights -> MFMA-fragment-native layout ----
// WT[kq][n] : 16B group = W[n][kq*8 .. kq*8+7]  (kq 0..63 = W_hh, 64..67 = W_ih pad32)
// B-frag load for chunk c: lane(col,quad) reads WT[c*4+quad][n0+col] -> 4x256B segments.
__global__ __launch_bounds__(256) void prep_whh_t(const float* __restrict__ W,
                                                  short* __restrict__ WTh, short* __restrict__ WTl) {
    int i = blockIdx.x * 256 + threadIdx.x;   // 2048 n x 64 kq = 131072, grid 512
    int n = i & 2047, kq = i >> 11;
    float v[8];
    #pragma unroll
    for (int j = 0; j < 8; ++j) v[j] = W[(size_t)n * HH + kq * 8 + j];
    short8 h8, l8;
    #pragma unroll
    for (int j = 0; j < 8; ++j) { short h_, l_; split2(v[j], h_, l_); h8[j] = h_; l8[j] = l_; }
    ((short8*)WTh)[(size_t)kq * 2048 + n] = h8;
    ((short8*)WTl)[(size_t)kq * 2048 + n] = l8;
}

__global__ __launch_bounds__(256) void prep_wih_t(const float* __restrict__ W,
                                                  short* __restrict__ WTh, short* __restrict__ WTl) {
    int i = blockIdx.x * 256 + threadIdx.x;   // 2048 n x 4 kq = 8192, grid 32
    int n = i & 2047, kq4 = i >> 11;
    float v[8];
    #pragma unroll
    for (int j = 0; j < 8; ++j) {
        int k = kq4 * 8 + j;
        v[j] = (k < VV) ? W[(size_t)n * VV + k] : 0.0f;
    }
    short8 h8, l8;
    #pragma unroll
    for (int j = 0; j < 8; ++j) { short h_, l_; split2(v[j], h_, l_); h8[j] = h_; l8[j] = l_; }
    ((short8*)WTh)[(size_t)(64 + kq4) * 2048 + n] = h8;
    ((short8*)WTl)[(size_t)(64 + kq4) * 2048 + n] = l8;
}

// One LSTM timestep: BARRIER-FREE, NO LDS. Both A (h) and B (W) fragments
// stream register-direct from L2 in MFMA-native layout with a 1-chunk
// odd/even-slot lookahead -> compiler emits only fine-grained vmcnt waits
// (no vmcnt(0) barrier drains — the r4-r6 limiter).
// Block = 256 thr (4 waves) = 64 batch x 32 j (x4 gates); wave w: wm=w&1
// (32-batch half), wn=w>>1 (16-j half); wave tile 2 m-tiles x 4 gates.
// Grid: 512 blocks 1-D, swizzled so each XCD owns 2 j-groups -> its WT slice
// (531 KB) stays L2-resident across all 128 steps.
// 3-product hi/lo split: acc += Ah*Bh + Ah*Bl + Al*Bh.
__global__ __launch_bounds__(256, 2) void lstm_step(
    const float* __restrict__ msg, int t,
    const short* __restrict__ WTh, const short* __restrict__ WTl,
    const float* __restrict__ b_ih, const float* __restrict__ b_hh,
    const short* __restrict__ hin_h, const short* __restrict__ hin_l,
    short* __restrict__ hout_h, short* __restrict__ hout_l,
    float* __restrict__ c)
{
    // swizzle: bid[2:0]->XCD pair-group, bid[3]->by lsb, bid[8:4]->bx
    const int bid = blockIdx.x;
    const int by = (bid & 7) * 2 + ((bid >> 3) & 1);
    const int bx = bid >> 4;
    const int b0 = bx * 64;
    const int j0 = by * 32;

    const int tid = threadIdx.x;
    const int lane = tid & 63;
    const int w = tid >> 6;
    const int wm = w & 1, wn = w >> 1;
    const int col = lane & 15, quad = lane >> 4;
    const int jj = j0 + wn * 16 + col;

    f32x4 acc[2][4];   // [tm][gate]
    #pragma unroll
    for (int g = 0; g < 4; ++g) {
        float bias = b_ih[g * HH + jj] + b_hh[g * HH + jj];
        f32x4 bv = {bias, bias, bias, bias};
        acc[0][g] = bv;
        acc[1][g] = bv;
    }

    // A frag-direct row pointers: lane(col,quad) reads 8 k at quad*8
    const short* arow_h[2];
    const short* arow_l[2];
    #pragma unroll
    for (int tm = 0; tm < 2; ++tm) {
        size_t base = (size_t)(b0 + wm * 32 + tm * 16 + col) * HH + quad * 8;
        arow_h[tm] = hin_h + base;
        arow_l[tm] = hin_l + base;
    }
    const short8* WTh8 = (const short8*)WTh;
    const short8* WTl8 = (const short8*)WTl;
    int bidx[4];
    #pragma unroll
    for (int g = 0; g < 4; ++g) bidx[g] = quad * 2048 + g * HH + j0 + wn * 16 + col;

    // odd/even slot pipeline regs
    short8 a_h[2][2], a_l[2][2];   // [slot][tm]
    short8 b_h[2][4], b_l[2][4];   // [slot][gate]

    // prologue: chunks 0 (slot0) and 1 (slot1)
    #pragma unroll
    for (int s = 0; s < 2; ++s) {
        #pragma unroll
        for (int tm = 0; tm < 2; ++tm) {
            a_h[s][tm] = *(const short8*)(arow_h[tm] + s * 32);
            a_l[s][tm] = *(const short8*)(arow_l[tm] + s * 32);
        }
        #pragma unroll
        for (int g = 0; g < 4; ++g) {
            b_h[s][g] = WTh8[s * 8192 + bidx[g]];
            b_l[s][g] = WTl8[s * 8192 + bidx[g]];
        }
    }

    // chunks 0..13: MFMA slot cc&1, prefetch chunk cc+2 into same slot
    for (int it = 0; it < 7; ++it) {
        #pragma unroll
        for (int s = 0; s < 2; ++s) {
            #pragma unroll
            for (int tm = 0; tm < 2; ++tm)
                #pragma unroll
                for (int g = 0; g < 4; ++g) {
                    acc[tm][g] = __builtin_amdgcn_mfma_f32_16x16x32_bf16(a_h[s][tm], b_h[s][g], acc[tm][g], 0, 0, 0);
                    acc[tm][g] = __builtin_amdgcn_mfma_f32_16x16x32_bf16(a_h[s][tm], b_l[s][g], acc[tm][g], 0, 0, 0);
                    acc[tm][g] = __builtin_amdgcn_mfma_f32_16x16x32_bf16(a_l[s][tm], b_h[s][g], acc[tm][g], 0, 0, 0);
                }
            const int nc = it * 2 + s + 2;   // 2..15
            #pragma unroll
            for (int tm = 0; tm < 2; ++tm) {
                a_h[s][tm] = *(const short8*)(arow_h[tm] + nc * 32);
                a_l[s][tm] = *(const short8*)(arow_l[tm] + nc * 32);
            }
            #pragma unroll
            for (int g = 0; g < 4; ++g) {
                b_h[s][g] = WTh8[nc * 8192 + bidx[g]];
                b_l[s][g] = WTl8[nc * 8192 + bidx[g]];
            }
        }
    }

    // chunk 14 (slot0): MFMA, then prefetch x-tail (chunk 16) into slot0
    #pragma unroll
    for (int tm = 0; tm < 2; ++tm)
        #pragma unroll
        for (int g = 0; g < 4; ++g) {
            acc[tm][g] = __builtin_amdgcn_mfma_f32_16x16x32_bf16(a_h[0][tm], b_h[0][g], acc[tm][g], 0, 0, 0);
            acc[tm][g] = __builtin_amdgcn_mfma_f32_16x16x32_bf16(a_h[0][tm], b_l[0][g], acc[tm][g], 0, 0, 0);
            acc[tm][g] = __builtin_amdgcn_mfma_f32_16x16x32_bf16(a_l[0][tm], b_h[0][g], acc[tm][g], 0, 0, 0);
        }
    #pragma unroll
    for (int tm = 0; tm < 2; ++tm) {
        const float* mrow = msg + ((size_t)(b0 + wm * 32 + tm * 16 + col) * TT + t) * VV;
        short8 xh, xl;
        #pragma unroll
        for (int i = 0; i < 8; ++i) {
            int k = quad * 8 + i;
            float v = (k < VV) ? mrow[k] : 0.0f;
            short h_, l_; split2(v, h_, l_);
            xh[i] = h_; xl[i] = l_;
        }
        a_h[0][tm] = xh; a_l[0][tm] = xl;
    }
    #pragma unroll
    for (int g = 0; g < 4; ++g) {
        b_h[0][g] = WTh8[16 * 8192 + bidx[g]];
        b_l[0][g] = WTl8[16 * 8192 + bidx[g]];
    }

    // chunk 15 (slot1): MFMA, no prefetch
    #pragma unroll
    for (int tm = 0; tm < 2; ++tm)
        #pragma unroll
        for (int g = 0; g < 4; ++g) {
            acc[tm][g] = __builtin_amdgcn_mfma_f32_16x16x32_bf16(a_h[1][tm], b_h[1][g], acc[tm][g], 0, 0, 0);
            acc[tm][g] = __builtin_amdgcn_mfma_f32_16x16x32_bf16(a_h[1][tm], b_l[1][g], acc[tm][g], 0, 0, 0);
            acc[tm][g] = __builtin_amdgcn_mfma_f32_16x16x32_bf16(a_l[1][tm], b_h[1][g], acc[tm][g], 0, 0, 0);
        }

    // chunk 16 (slot0): x-projection tail
    #pragma unroll
    for (int tm = 0; tm < 2; ++tm)
        #pragma unroll
        for (int g = 0; g < 4; ++g) {
            acc[tm][g] = __builtin_amdgcn_mfma_f32_16x16x32_bf16(a_h[0][tm], b_h[0][g], acc[tm][g], 0, 0, 0);
            acc[tm][g] = __builtin_amdgcn_mfma_f32_16x16x32_bf16(a_h[0][tm], b_l[0][g], acc[tm][g], 0, 0, 0);
            acc[tm][g] = __builtin_amdgcn_mfma_f32_16x16x32_bf16(a_l[0][tm], b_h[0][g], acc[tm][g], 0, 0, 0);
        }

    // ---- cell update; h written as bf16 hi/lo planes ----
    // C/D layout: col=lane&15 (=n), row=quad*4+reg  [m89]
    #pragma unroll
    for (int tm = 0; tm < 2; ++tm) {
        #pragma unroll
        for (int reg = 0; reg < 4; ++reg) {
            int b = b0 + wm * 32 + tm * 16 + quad * 4 + reg;
            size_t idx = (size_t)b * HH + jj;
            float i_ = fsigmoid(acc[tm][0][reg]);
            float f_ = fsigmoid(acc[tm][1][reg]);
            float g_ = ftanh(acc[tm][2][reg]);
            float o_ = fsigmoid(acc[tm][3][reg]);
            float cn = f_ * c[idx] + i_ * g_;
            c[idx] = cn;
            float h = o_ * ftanh(cn);
            short hh_, hl_; split2(h, hh_, hl_);
            hout_h[idx] = hh_;
            hout_l[idx] = hl_;
        }
    }
}

// out[b, cls] = dot(h, W_fc[cls]) + b_fc[cls]; h = hi + lo. 4 rows/block.
__global__ __launch_bounds__(256) void fc_kernel(
    const short* __restrict__ h_hi, const short* __restrict__ h_lo,
    const float* __restrict__ W_fc, const float* __restrict__ b_fc,
    float* __restrict__ out)
{
    __shared__ float hs[4][HH];
    const int b0 = blockIdx.x * 4;
    for (int i = threadIdx.x; i < 4 * HH; i += 256) {
        int r = i >> 9, k = i & 511;
        size_t idx = (size_t)(b0 + r) * HH + k;
        unsigned uh = (unsigned)(unsigned short)h_hi[idx];
        unsigned ul = (unsigned)(unsigned short)h_lo[idx];
        hs[r][k] = __uint_as_float(uh << 16) + __uint_as_float(ul << 16);
    }
    __syncthreads();
    const int tid = threadIdx.x;
    if (tid < 2 * NC) {
        int r = tid / NC, cls = tid % NC;
        const float4* wv = (const float4*)(W_fc + (size_t)cls * HH);
        const float4* h0 = (const float4*)hs[r];
        const float4* h1 = (const float4*)hs[r + 2];
        float s0 = 0.0f, s1 = 0.0f;
        #pragma unroll 4
        for (int k = 0; k < HH / 4; ++k) {
            float4 ww = wv[k];
            float4 a0 = h0[k], a1 = h1[k];
            s0 += a0.x * ww.x + a0.y * ww.y + a0.z * ww.z + a0.w * ww.w;
            s1 += a1.x * ww.x + a1.y * ww.y + a1.z * ww.z + a1.w * ww.w;
        }
        out[(size_t)(b0 + r) * NC + cls] = s0 + b_fc[cls];
        out[(size_t)(b0 + r + 2) * NC + cls] = s1 + b_fc[cls];
    }
}

extern "C" void kernel_launch(void* const* d_in, const int* in_sizes, int n_in,
                              void* d_out, int out_size, void* d_ws, size_t ws_size,
                              hipStream_t stream) {
    const float* msg  = (const float*)d_in[0];
    const float* W_ih = (const float*)d_in[1];
    const float* W_hh = (const float*)d_in[2];
    const float* b_ih = (const float*)d_in[3];
    const float* b_hh = (const float*)d_in[4];
    const float* W_fc = (const float*)d_in[5];
    const float* b_fc = (const float*)d_in[6];
    float* out = (float*)d_out;

    // ws: c(4MB) | h0h h0l h1h h1l (2MB ea) | WTh WTl (2.125MB ea) = 16.25MB
    float* c   = (float*)d_ws;
    short* h0h = (short*)(c + (size_t)BB * HH);
    short* h0l = h0h + (size_t)BB * HH;
    short* h1h = h0l + (size_t)BB * HH;
    short* h1l = h1h + (size_t)BB * HH;
    short* WTh = h1l + (size_t)BB * HH;
    short* WTl = WTh + (size_t)68 * 2048 * 8;

    // zero c + h0 planes (contiguous 8 MB)
    hipMemsetAsync(d_ws, 0, (size_t)BB * HH * 4 + (size_t)BB * HH * 2 * 2, stream);

    prep_whh_t<<<512, 256, 0, stream>>>(W_hh, WTh, WTl);
    prep_wih_t<<<32, 256, 0, stream>>>(W_ih, WTh, WTl);

    short *hinh = h0h, *hinl = h0l, *houth = h1h, *houtl = h1l;
    for (int t = 0; t < TT; ++t) {
        lstm_step<<<512, 256, 0, stream>>>(
            msg, t, WTh, WTl, b_ih, b_hh, hinh, hinl, houth, houtl, c);
        short* tm1 = hinh; hinh = houth; houth = tm1;
        short* tm2 = hinl; hinl = houtl; houtl = tm2;
    }
    fc_kernel<<<BB / 4, 256, 0, stream>>>(hinh, hinl, W_fc, b_fc, out);
}

// Round 8
// 1782.182 us; speedup vs baseline: 2.3883x; 2.3883x over previous
//
#include <hip/hip_runtime.h>

// Problem constants
#define BB 2048   // batch
#define TT 128    // timesteps
#define VV 25     // input features
#define HH 512    // hidden
#define NC 100    // classes

typedef __attribute__((ext_vector_type(8))) short short8;
typedef __attribute__((ext_vector_type(4))) float f32x4;

__device__ __forceinline__ float fsigmoid(float x) { return 1.0f / (1.0f + __expf(-x)); }
__device__ __forceinline__ float ftanh(float x) {
    float e = __expf(2.0f * x);
    return 1.0f - 2.0f / (e + 1.0f);
}

// fp32 -> bf16 hi + bf16 lo (RNE both); hi+lo carries ~16 mantissa bits.
__device__ __forceinline__ void split2(float f, short& hi, short& lo) {
    unsigned u = __float_as_uint(f);
    unsigned hb = (u + 0x7FFFu + ((u >> 16) & 1u)) >> 16;
    float hf = __uint_as_float(hb << 16);
    float r = f - hf;                      // exact
    unsigned v = __float_as_uint(r);
    unsigned lb = (v + 0x7FFFu + ((v >> 16) & 1u)) >> 16;
    hi = (short)hb;
    lo = (short)lb;
}
__device__ __forceinline__ short bf16rne(float f) {
    unsigned u = __float_as_uint(f);
    return (short)((u + 0x7FFFu + ((u >> 16) & 1u)) >> 16);
}

// ---- prep: weights -> MFMA-fragment-native bf16 layout (hi plane only) ----
// WT[kq][n] : 16B group = bf16(W[n][kq*8 .. kq*8+7])  (kq 0..63 = W_hh,
// 64..67 = W_ih zero-padded to K=32).
// B-frag load for chunk c: lane(col,quad) reads WT[c*4+quad][n0+col] -> 4x256B segs.
__global__ __launch_bounds__(256) void prep_whh_t(const float* __restrict__ W,
                                                  short* __restrict__ WTh) {
    int i = blockIdx.x * 256 + threadIdx.x;   // 2048 n x 64 kq = 131072, grid 512
    int n = i & 2047, kq = i >> 11;
    short8 h8;
    #pragma unroll
    for (int j = 0; j < 8; ++j) h8[j] = bf16rne(W[(size_t)n * HH + kq * 8 + j]);
    ((short8*)WTh)[(size_t)kq * 2048 + n] = h8;   // consecutive tid -> consecutive n
}

__global__ __launch_bounds__(256) void prep_wih_t(const float* __restrict__ W,
                                                  short* __restrict__ WTh) {
    int i = blockIdx.x * 256 + threadIdx.x;   // 2048 n x 4 kq = 8192, grid 32
    int n = i & 2047, kq4 = i >> 11;
    short8 h8;
    #pragma unroll
    for (int j = 0; j < 8; ++j) {
        int k = kq4 * 8 + j;
        h8[j] = (k < VV) ? bf16rne(W[(size_t)n * VV + k]) : (short)0;
    }
    ((short8*)WTh)[(size_t)(64 + kq4) * 2048 + n] = h8;
}

// One LSTM timestep. Block = 256 thr (4 waves) = 64 batch x 32 j (x4 gates).
// Grid (32,16) = 512 blocks = 2 blocks/CU, 8 waves/CU = 2 waves/SIMD.
// Wave w: wm=w&1 -> 32-batch half, wn=w>>1 -> 16-j half. Wave tile:
// 2 m-tiles x 4 gates of 16x16x32 bf16. B-frags (bf16, single plane) stream
// register-direct from L2 (frag-native WT; wm-twin waves hit L1 on the same
// lines); A (h) hi/lo via double-buffered LDS, ONE barrier per K64.
// 2-product split: acc += Ah*Bh + Al*Bh  (A fp32-exact, B rounded once).
__global__ __launch_bounds__(256, 2) void lstm_step(
    const float* __restrict__ msg, int t,
    const short* __restrict__ WTh,
    const float* __restrict__ b_ih, const float* __restrict__ b_hh,
    const short* __restrict__ hin_h, const short* __restrict__ hin_l,
    short* __restrict__ hout_h, short* __restrict__ hout_l,
    float* __restrict__ c)
{
    const int b0 = blockIdx.x * 64;
    const int j0 = blockIdx.y * 32;
    const int tid = threadIdx.x;
    const int lane = tid & 63;
    const int w = tid >> 6;
    const int wm = w & 1, wn = w >> 1;
    const int col = lane & 15, quad = lane >> 4;
    const int jj = j0 + wn * 16 + col;

    // [buf][plane][row][k]; row stride 72 (pad 8): frag b128 reads conflict-free.
    __shared__ short Abuf[2][2][64][72];   // 36.9 KB -> 2 blocks/CU

    f32x4 acc[2][4];   // [tm][gate]
    #pragma unroll
    for (int g = 0; g < 4; ++g) {
        float bias = b_ih[g * HH + jj] + b_hh[g * HH + jj];
        f32x4 bv = {bias, bias, bias, bias};
        acc[0][g] = bv;
        acc[1][g] = bv;
    }

    // A staging: thread -> (row = tid>>2, 16-k segment = (tid&3)*16)
    const int arow = tid >> 2, aseg = (tid & 3) << 4;
    const short* aph = hin_h + (size_t)(b0 + arow) * HH + aseg;
    const short* apl = hin_l + (size_t)(b0 + arow) * HH + aseg;

    const short8* WTh8 = (const short8*)WTh;
    int bidx[4];
    #pragma unroll
    for (int g = 0; g < 4; ++g) bidx[g] = quad * 2048 + g * HH + j0 + wn * 16 + col;

    short8 Bh[2][4];                // B double-buffer regs (chunk parity)
    short8 ra_h[2], ra_l[2];        // staged A regs (next K64 chunk)

    // ---- prologue: K64 chunk0 -> LDS buf0; chunk1 -> ra; B chunks 0,1 ----
    ra_h[0] = *(const short8*)(aph);     ra_h[1] = *(const short8*)(aph + 8);
    ra_l[0] = *(const short8*)(apl);     ra_l[1] = *(const short8*)(apl + 8);
    #pragma unroll
    for (int g = 0; g < 4; ++g) Bh[0][g] = WTh8[bidx[g]];
    *(short8*)&Abuf[0][0][arow][aseg]     = ra_h[0];
    *(short8*)&Abuf[0][0][arow][aseg + 8] = ra_h[1];
    *(short8*)&Abuf[0][1][arow][aseg]     = ra_l[0];
    *(short8*)&Abuf[0][1][arow][aseg + 8] = ra_l[1];
    ra_h[0] = *(const short8*)(aph + 64); ra_h[1] = *(const short8*)(aph + 72);
    ra_l[0] = *(const short8*)(apl + 64); ra_l[1] = *(const short8*)(apl + 72);
    #pragma unroll
    for (int g = 0; g < 4; ++g) Bh[1][g] = WTh8[8192 + bidx[g]];
    __syncthreads();

    float xv[8];                         // msg tail values
    const int xrow = tid >> 2, xseg = (tid & 3) << 3;

    for (int it = 0; it < 8; ++it) {
        const int buf = it & 1;
        #pragma unroll
        for (int kk = 0; kk < 2; ++kk) {
            const int cchunk = it * 2 + kk;
            const int p = cchunk & 1;
            short8 ahf[2], alf[2];
            #pragma unroll
            for (int tm = 0; tm < 2; ++tm) {
                int row = wm * 32 + tm * 16 + col;
                ahf[tm] = *(const short8*)&Abuf[buf][0][row][kk * 32 + quad * 8];
                alf[tm] = *(const short8*)&Abuf[buf][1][row][kk * 32 + quad * 8];
            }
            #pragma unroll
            for (int tm = 0; tm < 2; ++tm)
                #pragma unroll
                for (int g = 0; g < 4; ++g) {
                    acc[tm][g] = __builtin_amdgcn_mfma_f32_16x16x32_bf16(ahf[tm], Bh[p][g], acc[tm][g], 0, 0, 0);
                    acc[tm][g] = __builtin_amdgcn_mfma_f32_16x16x32_bf16(alf[tm], Bh[p][g], acc[tm][g], 0, 0, 0);
                }
            // prefetch B for chunk+2 into slot just consumed (chunk 16 = Wih tail)
            if (cchunk + 2 <= 16) {
                const int ix = (cchunk + 2) * 8192;
                #pragma unroll
                for (int g = 0; g < 4; ++g) Bh[p][g] = WTh8[ix + bidx[g]];
            }
        }
        if (it < 7) {
            *(short8*)&Abuf[buf ^ 1][0][arow][aseg]     = ra_h[0];   // ra = chunk it+1
            *(short8*)&Abuf[buf ^ 1][0][arow][aseg + 8] = ra_h[1];
            *(short8*)&Abuf[buf ^ 1][1][arow][aseg]     = ra_l[0];
            *(short8*)&Abuf[buf ^ 1][1][arow][aseg + 8] = ra_l[1];
            if (it < 6) {
                const int kt = (it + 2) * 64;
                ra_h[0] = *(const short8*)(aph + kt); ra_h[1] = *(const short8*)(aph + kt + 8);
                ra_l[0] = *(const short8*)(apl + kt); ra_l[1] = *(const short8*)(apl + kt + 8);
            } else {
                // it==6: load msg tail (K=25 padded to 32): row=tid>>2, 8 k's each
                const size_t mb = ((size_t)(b0 + xrow) * TT + t) * VV;
                #pragma unroll
                for (int i = 0; i < 8; ++i) {
                    int k = xseg + i;
                    xv[i] = (k < VV) ? msg[mb + k] : 0.0f;
                }
            }
        } else {
            // it==7: split + stage x-tail into buf0 (buf0 last read at it==6)
            short8 xh, xl;
            #pragma unroll
            for (int i = 0; i < 8; ++i) { short h_, l_; split2(xv[i], h_, l_); xh[i] = h_; xl[i] = l_; }
            *(short8*)&Abuf[0][0][xrow][xseg] = xh;
            *(short8*)&Abuf[0][1][xrow][xseg] = xl;
        }
        __syncthreads();
    }

    // ---- x-projection tail: chunk 16 (K=32), buf0, B slot 0 ----
    {
        short8 ahf[2], alf[2];
        #pragma unroll
        for (int tm = 0; tm < 2; ++tm) {
            int row = wm * 32 + tm * 16 + col;
            ahf[tm] = *(const short8*)&Abuf[0][0][row][quad * 8];
            alf[tm] = *(const short8*)&Abuf[0][1][row][quad * 8];
        }
        #pragma unroll
        for (int tm = 0; tm < 2; ++tm)
            #pragma unroll
            for (int g = 0; g < 4; ++g) {
                acc[tm][g] = __builtin_amdgcn_mfma_f32_16x16x32_bf16(ahf[tm], Bh[0][g], acc[tm][g], 0, 0, 0);
                acc[tm][g] = __builtin_amdgcn_mfma_f32_16x16x32_bf16(alf[tm], Bh[0][g], acc[tm][g], 0, 0, 0);
            }
    }

    // ---- cell update; h written as bf16 hi/lo planes ----
    // C/D layout: col=lane&15 (=n), row=quad*4+reg  [m89]
    #pragma unroll
    for (int tm = 0; tm < 2; ++tm) {
        #pragma unroll
        for (int reg = 0; reg < 4; ++reg) {
            int b = b0 + wm * 32 + tm * 16 + quad * 4 + reg;
            size_t idx = (size_t)b * HH + jj;
            float i_ = fsigmoid(acc[tm][0][reg]);
            float f_ = fsigmoid(acc[tm][1][reg]);
            float g_ = ftanh(acc[tm][2][reg]);
            float o_ = fsigmoid(acc[tm][3][reg]);
            float cn = f_ * c[idx] + i_ * g_;
            c[idx] = cn;
            float h = o_ * ftanh(cn);
            short hh_, hl_; split2(h, hh_, hl_);
            hout_h[idx] = hh_;
            hout_l[idx] = hl_;
        }
    }
}

// out[b, cls] = dot(h, W_fc[cls]) + b_fc[cls]; h = hi + lo. 4 rows/block.
__global__ __launch_bounds__(256) void fc_kernel(
    const short* __restrict__ h_hi, const short* __restrict__ h_lo,
    const float* __restrict__ W_fc, const float* __restrict__ b_fc,
    float* __restrict__ out)
{
    __shared__ float hs[4][HH];
    const int b0 = blockIdx.x * 4;
    for (int i = threadIdx.x; i < 4 * HH; i += 256) {
        int r = i >> 9, k = i & 511;
        size_t idx = (size_t)(b0 + r) * HH + k;
        unsigned uh = (unsigned)(unsigned short)h_hi[idx];
        unsigned ul = (unsigned)(unsigned short)h_lo[idx];
        hs[r][k] = __uint_as_float(uh << 16) + __uint_as_float(ul << 16);
    }
    __syncthreads();
    const int tid = threadIdx.x;
    if (tid < 2 * NC) {
        int r = tid / NC, cls = tid % NC;
        const float4* wv = (const float4*)(W_fc + (size_t)cls * HH);
        const float4* h0 = (const float4*)hs[r];
        const float4* h1 = (const float4*)hs[r + 2];
        float s0 = 0.0f, s1 = 0.0f;
        #pragma unroll 4
        for (int k = 0; k < HH / 4; ++k) {
            float4 ww = wv[k];
            float4 a0 = h0[k], a1 = h1[k];
            s0 += a0.x * ww.x + a0.y * ww.y + a0.z * ww.z + a0.w * ww.w;
            s1 += a1.x * ww.x + a1.y * ww.y + a1.z * ww.z + a1.w * ww.w;
        }
        out[(size_t)(b0 + r) * NC + cls] = s0 + b_fc[cls];
        out[(size_t)(b0 + r + 2) * NC + cls] = s1 + b_fc[cls];
    }
}

extern "C" void kernel_launch(void* const* d_in, const int* in_sizes, int n_in,
                              void* d_out, int out_size, void* d_ws, size_t ws_size,
                              hipStream_t stream) {
    const float* msg  = (const float*)d_in[0];
    const float* W_ih = (const float*)d_in[1];
    const float* W_hh = (const float*)d_in[2];
    const float* b_ih = (const float*)d_in[3];
    const float* b_hh = (const float*)d_in[4];
    const float* W_fc = (const float*)d_in[5];
    const float* b_fc = (const float*)d_in[6];
    float* out = (float*)d_out;

    // ws: c(4MB) | h0h h0l h1h h1l (2MB ea) | WTh (2.23MB) = 14.2MB
    float* c   = (float*)d_ws;
    short* h0h = (short*)(c + (size_t)BB * HH);
    short* h0l = h0h + (size_t)BB * HH;
    short* h1h = h0l + (size_t)BB * HH;
    short* h1l = h1h + (size_t)BB * HH;
    short* WTh = h1l + (size_t)BB * HH;

    // zero c + h0 planes (contiguous 8 MB)
    hipMemsetAsync(d_ws, 0, (size_t)BB * HH * 4 + (size_t)BB * HH * 2 * 2, stream);

    prep_whh_t<<<512, 256, 0, stream>>>(W_hh, WTh);
    prep_wih_t<<<32, 256, 0, stream>>>(W_ih, WTh);

    short *hinh = h0h, *hinl = h0l, *houth = h1h, *houtl = h1l;
    for (int t = 0; t < TT; ++t) {
        lstm_step<<<dim3(BB / 64, HH / 32), 256, 0, stream>>>(
            msg, t, WTh, b_ih, b_hh, hinh, hinl, houth, houtl, c);
        short* tm1 = hinh; hinh = houth; houth = tm1;
        short* tm2 = hinl; hinl = houtl; houtl = tm2;
    }
    fc_kernel<<<BB / 4, 256, 0, stream>>>(hinh, hinl, W_fc, b_fc, out);
}